// Round 1
// baseline (174.871 us; speedup 1.0000x reference)
//
#include <hip/hip_runtime.h>
#include <math.h>

// Problem constants (from reference):
//   SR = DOWN_SR = 16000, FRAME_TIME = 0.01 -> STRIDES = 160
//   TAU_MAX = 213, TAU_MIN = 26, W = 257, C = 187
//   MEDIAN_WIN = 30, THRESHOLD = 0.1
#define T_LEN    160000
#define STRIDES  160
#define NF       1001          // frames per batch = T//STRIDES + 1
#define NB       64
#define W_LEN    257
#define TAU_MAXC 213
#define TAU_MINC 26
#define C_LEN    187           // TAU_MAX - TAU_MIN
#define SPAD     520           // zero-padded LDS signal (covers t0+j+11 max = 515)
#define NFRAMES  (NB * NF)     // 64064, divisible by 4

__global__ __launch_bounds__(256) void yin_frames(const float* __restrict__ in,
                                                  float* __restrict__ pitch) {
    __shared__ __align__(16) float s_sm[4][SPAD];
    __shared__ __align__(16) float cs_sm[4][260];   // cumsum of squares, idx 0..256
    __shared__ __align__(16) float cm_sm[4][216];   // cmnd_full, idx 0..212 used

    const int wid  = threadIdx.x >> 6;
    const int lane = threadIdx.x & 63;
    const int frame = blockIdx.x * 4 + wid;         // grid sized exactly NFRAMES/4
    const int b = frame / NF;
    const int f = frame - b * NF;

    float* s  = s_sm[wid];
    float* cs = cs_sm[wid];
    float* cm = cm_sm[wid];

    // ---- stage frame into LDS, zero-padded ----
    const float* src = in + (size_t)b * T_LEN;
    const int start = f * STRIDES;
    for (int j = lane; j < SPAD; j += 64) {
        int g = start + j;
        s[j] = (j < W_LEN && g < T_LEN) ? src[g] : 0.0f;
    }
    __syncthreads();

    // ---- autocorrelation: lane owns taus t0..t0+3, rolling 8-float window ----
    const int t0 = lane * 4;
    float a0 = 0.f, a1 = 0.f, a2 = 0.f, a3 = 0.f;
    float4 ra = *(const float4*)(s + t0);
    float4 rb = *(const float4*)(s + t0 + 4);
    for (int j = 0; j < 256; j += 4) {
        float4 c = *(const float4*)(s + j);   // wave-uniform broadcast read
        a0 = fmaf(c.x, ra.x, a0); a1 = fmaf(c.x, ra.y, a1); a2 = fmaf(c.x, ra.z, a2); a3 = fmaf(c.x, ra.w, a3);
        a0 = fmaf(c.y, ra.y, a0); a1 = fmaf(c.y, ra.z, a1); a2 = fmaf(c.y, ra.w, a2); a3 = fmaf(c.y, rb.x, a3);
        a0 = fmaf(c.z, ra.z, a0); a1 = fmaf(c.z, ra.w, a1); a2 = fmaf(c.z, rb.x, a2); a3 = fmaf(c.z, rb.y, a3);
        a0 = fmaf(c.w, ra.w, a0); a1 = fmaf(c.w, rb.x, a1); a2 = fmaf(c.w, rb.y, a2); a3 = fmaf(c.w, rb.z, a3);
        ra = rb;
        rb = *(const float4*)(s + t0 + j + 8);
    }

    // ---- cumsum of squares (wave scan, 4 elems/lane) ----
    float4 v = *(const float4*)(s + t0);
    float p0 = v.x * v.x;
    float p1 = p0 + v.y * v.y;
    float p2 = p1 + v.z * v.z;
    float p3 = p2 + v.w * v.w;
    float sc = p3;
#pragma unroll
    for (int off = 1; off < 64; off <<= 1) {
        float o = __shfl_up(sc, off);
        if (lane >= off) sc += o;
    }
    float base = sc - p3;
    float4 csv;
    csv.x = base + p0; csv.y = base + p1; csv.z = base + p2; csv.w = base + p3;
    *(float4*)(cs + t0) = csv;
    if (lane == 63) cs[256] = sc + s[256] * s[256];
    __syncthreads();

    // ---- diff + cumulative-mean normalization ----
    const float totE = cs[256];
    float d0 = cs[256 - (t0 + 0)] - 2.0f * a0 + totE - csv.x;
    float d1 = cs[256 - (t0 + 1)] - 2.0f * a1 + totE - csv.y;
    float d2 = cs[256 - (t0 + 2)] - 2.0f * a2 + totE - csv.z;
    float d3 = cs[256 - (t0 + 3)] - 2.0f * a3 + totE - csv.w;
    if (lane == 0) d0 = 0.0f;                       // diff[0] excluded from prefix
    float l0 = d0, l1 = l0 + d1, l2 = l1 + d2, l3 = l2 + d3;
    float scn = l3;
#pragma unroll
    for (int off = 1; off < 64; off <<= 1) {
        float o = __shfl_up(scn, off);
        if (lane >= off) scn += o;
    }
    float pb = scn - l3;                            // exclusive base
    float cd0 = d0 * (float)(t0 + 0) / (pb + l0 + 1e-7f);
    float cd1 = d1 * (float)(t0 + 1) / (pb + l1 + 1e-7f);
    float cd2 = d2 * (float)(t0 + 2) / (pb + l2 + 1e-7f);
    float cd3 = d3 * (float)(t0 + 3) / (pb + l3 + 1e-7f);
    if (t0 <= 212) {
        float4 cdv;
        cdv.x = (t0 == 0) ? 1.0f : cd0;
        cdv.y = cd1; cdv.z = cd2; cdv.w = cd3;
        *(float4*)(cm + t0) = cdv;
    }
    __syncthreads();

    // ---- threshold search: first i with cmnd[i] < 0.1 ; 0 or none -> C ----
    int tholdCand = 999;
    {
        int i = lane;
#pragma unroll
        for (int r = 0; r < 3; ++r, i += 64) {
            if (i < C_LEN && cm[TAU_MINC + i] < 0.1f && i < tholdCand) tholdCand = i;
        }
    }
#pragma unroll
    for (int off = 32; off; off >>= 1) {
        int o = __shfl_xor(tholdCand, off);
        if (o < tholdCand) tholdCand = o;
    }
    const int thold = (tholdCand == 0 || tholdCand == 999) ? C_LEN : tholdCand;

    // ---- tau: first i >= thold that is a local min ----
    int tauCand = 999;
    {
        int i = lane;
#pragma unroll
        for (int r = 0; r < 3; ++r, i += 64) {
            if (i < C_LEN && i >= thold && i < tauCand) {
                float xc = cm[TAU_MINC + i];
                bool left  = (i == 0) || (xc - cm[TAU_MINC + i - 1] <= 0.0f);
                bool right = (i == C_LEN - 1) || (cm[TAU_MINC + i + 1] - xc >= 0.0f);
                if (left && right) tauCand = i;
            }
        }
    }
#pragma unroll
    for (int off = 32; off; off >>= 1) {
        int o = __shfl_xor(tauCand, off);
        if (o < tauCand) tauCand = o;
    }
    const int tau = (tauCand == 999) ? 0 : tauCand;

    if (lane == 0) {
        float shift = 0.0f;
        if (tau >= 1 && tau <= C_LEN - 2) {
            float p = cm[TAU_MINC + tau - 1];
            float c = cm[TAU_MINC + tau];
            float n = cm[TAU_MINC + tau + 1];
            float aa = n + p - 2.0f * c;
            float bb = 0.5f * (n - p);
            shift = (fabsf(bb) >= fabsf(aa)) ? 0.0f : (-bb / aa);
        }
        float pv = (tau > 0) ? (16000.0f / ((float)(tau + TAU_MINC + 1) + shift)) : 0.0f;
        pitch[frame] = pv;
    }
}

// 30-wide median (15th smallest, index 14 of ascending sort), edge-padded (15,14)
__global__ __launch_bounds__(256) void median_k(const float* __restrict__ pitch,
                                                float* __restrict__ out) {
    int idx = blockIdx.x * blockDim.x + threadIdx.x;
    if (idx >= NFRAMES) return;
    int b = idx / NF;
    int f = idx - b * NF;
    const float* p = pitch + b * NF;
    float v[30];
#pragma unroll
    for (int k = 0; k < 30; ++k) {
        int j = f + k - 15;
        j = (j < 0) ? 0 : ((j > NF - 1) ? NF - 1 : j);
        v[k] = p[j];
    }
    float result = 0.0f;
#pragma unroll 1
    for (int i = 0; i < 30; ++i) {
        int lt = 0, le = 0;
#pragma unroll
        for (int j = 0; j < 30; ++j) {
            lt += (v[j] < v[i]);
            le += (v[j] <= v[i]);
        }
        if (lt <= 14 && 14 < le) result = v[i];
    }
    out[idx] = result;
}

extern "C" void kernel_launch(void* const* d_in, const int* in_sizes, int n_in,
                              void* d_out, int out_size, void* d_ws, size_t ws_size,
                              hipStream_t stream) {
    (void)in_sizes; (void)n_in; (void)out_size; (void)ws_size;
    const float* in = (const float*)d_in[0];
    float* out = (float*)d_out;
    float* pitch = (float*)d_ws;     // NFRAMES floats = 256 KB scratch

    yin_frames<<<NFRAMES / 4, 256, 0, stream>>>(in, pitch);
    median_k<<<(NFRAMES + 255) / 256, 256, 0, stream>>>(pitch, out);
}